// Round 10
// baseline (267.755 us; speedup 1.0000x reference)
//
#include <hip/hip_runtime.h>
#include <math.h>

#define TOK 16384
#define DD  2048
#define EE  64
#define MT  32           // tokens per block
#define BK  128          // k per chunk = 4 MFMA sub-steps of 32
#define NKC 8            // chunks per K-group (group covers 1024)
#define LDA 138          // halves per token row per split (276B = 69-word stride, odd)
#define XREG (MT * LDA)  // halves per (g,buf,split) region
#define NBLK (TOK / MT)  // 512 gating blocks

typedef _Float16 half4v __attribute__((ext_vector_type(4)));
typedef _Float16 half8  __attribute__((ext_vector_type(8)));
typedef float    floatx4 __attribute__((ext_vector_type(4)));

// ---- W pre-split: f32 -> (hi,lo) f16, frag-major layout ----
// wf frag index ((ct*64+kc)*2+s)*64+lane, 8 halves each (kc = 32-k chunk 0..63).
// ct 0..3 = gate col-tiles (cols ct*16+cl), ct 4..7 = noise col-tiles.
// Block 0 also zeroes the aux workspace (stream order covers gating_kernel).
__global__ void build_wf(const float* __restrict__ Wg, const float* __restrict__ Wn,
                         _Float16* __restrict__ wf, float* __restrict__ zws) {
  if (blockIdx.x == 0 && threadIdx.x < 128) zws[threadIdx.x] = 0.f;
  int tid  = blockIdx.x * 128 + threadIdx.x;   // 32768 threads
  int lane = tid & 63;
  int kc   = (tid >> 6) & 63;
  int ct   = tid >> 12;                        // 0..7
  int col  = (ct & 3) * 16 + (lane & 15);
  int k    = kc * 32 + (lane >> 4) * 8;
  const float* W = (ct < 4) ? Wg : Wn;
  const float* src = W + (size_t)col * DD + k;
  float4 a = *reinterpret_cast<const float4*>(src);
  float4 b = *reinterpret_cast<const float4*>(src + 4);
  float v[8] = {a.x, a.y, a.z, a.w, b.x, b.y, b.z, b.w};
  half8 hi, lo;
#pragma unroll
  for (int j = 0; j < 8; ++j) {
    _Float16 h = (_Float16)v[j];
    hi[j] = h;
    lo[j] = (_Float16)(v[j] - (float)h);
  }
  size_t base = (((size_t)(ct * 64 + kc) * 2 + 0) * 64 + lane) * 8;
  *reinterpret_cast<half8*>(wf + base)       = hi;
  *reinterpret_cast<half8*>(wf + base + 512) = lo;
}

// Convert+store one 128-float chunk row-slice (4x float4) into buffer BUF.
#define STAGE(BUF, P0, P1, P2, P3)                                              \
  {                                                                             \
    float4 pav[4] = {P0, P1, P2, P3};                                           \
    _Float16* xh = xs + ((g * 2 + (BUF)) * 2 + 0) * XREG + stok * LDA + skof;   \
    _Float16* xl = xh + XREG;                                                   \
    _Pragma("unroll")                                                           \
    for (int j = 0; j < 4; ++j) {                                               \
      float v[4] = {pav[j].x, pav[j].y, pav[j].z, pav[j].w};                    \
      half4v hi, lo;                                                            \
      _Pragma("unroll")                                                         \
      for (int jj = 0; jj < 4; ++jj) {                                          \
        _Float16 h = (_Float16)v[jj];                                           \
        hi[jj] = h;                                                             \
        lo[jj] = (_Float16)(v[jj] - (float)h);                                  \
      }                                                                         \
      *reinterpret_cast<half4v*>(xh + j * 32) = hi;                             \
      *reinterpret_cast<half4v*>(xl + j * 32) = lo;                             \
    }                                                                           \
  }

// One 32-k MFMA sub-step. Consume slot SC (loaded 3 sub-steps ago); issue the
// loads for sub-step KK+3 into slot SPF BEFORE the MFMAs, so ~2 full sub-step
// bodies (~160-320 cy) of issue distance cover L2 latency. Cross-chunk loads
// stay in flight through the counted (lgkm-only) barrier. MFMA order
// (hi*hi, hi*lo, lo*hi) identical to the verified kernel.
#define SUBK(KK, SC, SPF, DOPF)                                                 \
  {                                                                             \
    half8 Ah[2], Al[2];                                                         \
    _Pragma("unroll")                                                           \
    for (int mt = 0; mt < 2; ++mt) {                                            \
      Ah[mt] = *reinterpret_cast<const half8*>(xsh + (mt * 16) * LDA + (KK) * 32); \
      Al[mt] = *reinterpret_cast<const half8*>(xsl + (mt * 16) * LDA + (KK) * 32); \
    }                                                                           \
    if (DOPF) {                                                                 \
      const int ck = g * 32 + kc * 4 + (KK) + 3;                                \
      _Pragma("unroll")                                                         \
      for (int nt = 0; nt < 2; ++nt) {                                          \
        const int ct = w4 + nt * 4;                                             \
        _Pragma("unroll")                                                       \
        for (int s = 0; s < 2; ++s)                                             \
          SPF[nt][s] = wfp[((size_t)(ct * 64 + ck) * 2 + s) * 64 + l];          \
      }                                                                         \
    }                                                                           \
    _Pragma("unroll")                                                           \
    for (int mt = 0; mt < 2; ++mt)                                              \
      _Pragma("unroll")                                                         \
      for (int nt = 0; nt < 2; ++nt)                                            \
        acc[mt][nt] = __builtin_amdgcn_mfma_f32_16x16x32_f16(Ah[mt], SC[nt][0], acc[mt][nt], 0, 0, 0); \
    _Pragma("unroll")                                                           \
    for (int mt = 0; mt < 2; ++mt)                                              \
      _Pragma("unroll")                                                         \
      for (int nt = 0; nt < 2; ++nt)                                            \
        acc[mt][nt] = __builtin_amdgcn_mfma_f32_16x16x32_f16(Ah[mt], SC[nt][1], acc[mt][nt], 0, 0, 0); \
    _Pragma("unroll")                                                           \
    for (int mt = 0; mt < 2; ++mt)                                              \
      _Pragma("unroll")                                                         \
      for (int nt = 0; nt < 2; ++nt)                                            \
        acc[mt][nt] = __builtin_amdgcn_mfma_f32_16x16x32_f16(Al[mt], SC[nt][0], acc[mt][nt], 0, 0, 0); \
  }

// LDS plan:
//   K-phase : xs[(g*2+buf)*2+split][32*LDA] halves = 8 regions x 8832 B = 70656 B
//   E-phase : overlay — Pacc 64x64 f32 @0 | Vb[32][66] @16384 | Eb[32][66] @24832
//             isum @33280 | ti @33408 | tp @33664  (33920 B < 70656)
__global__ __launch_bounds__(512, 4)
void gating_kernel(const float* __restrict__ x, const float* __restrict__ rn,
                   const _Float16* __restrict__ wf, const float* __restrict__ bg,
                   float* __restrict__ out,
                   float* __restrict__ cnt_g, float* __restrict__ psum_g) {
  __shared__ char smem[70656];
  _Float16* xs   = (_Float16*)smem;
  float*    Pacc = (float*)smem;
  float*    Vb   = (float*)(smem + 16384);
  float*    Eb   = (float*)(smem + 24832);
  float*    isum = (float*)(smem + 33280);
  int*      ti   = (int*)(smem + 33408);
  float*    tp   = (float*)(smem + 33664);

  const int t  = threadIdx.x;
  const int g  = t >> 8;        // K-group: 0 -> K[0,1024), 1 -> K[1024,2048)
  const int tg = t & 255;
  const int w4 = tg >> 6;       // ct-pair 0..3 -> expert cols [w4*16, +16)
  const int l  = t & 63;
  const int q  = l >> 4;
  const int cl = l & 15;
  const int c  = w4 * 16 + cl;
  const int t0 = blockIdx.x * MT;

  // x staging (per group): thread covers token tg>>3, float-offset (tg&7)*4
  const int stok = tg >> 3;
  const int skof = (tg & 7) * 4;
  const float* xrow = x + (size_t)(t0 + stok) * DD + g * (NKC * BK) + skof;

  // epilogue operands (group 0 only)
  float bgv = 0.f;
  float rnv[2][4] = {{0.f,0.f,0.f,0.f},{0.f,0.f,0.f,0.f}};
  if (g == 0) {
    bgv = bg[c];
#pragma unroll
    for (int mt = 0; mt < 2; ++mt)
#pragma unroll
      for (int r = 0; r < 4; ++r)
        rnv[mt][r] = rn[(size_t)(t0 + mt * 16 + q * 4 + r) * EE + c];
  }

  floatx4 acc[2][2];
#pragma unroll
  for (int mt = 0; mt < 2; ++mt)
#pragma unroll
    for (int nt = 0; nt < 2; ++nt) acc[mt][nt] = (floatx4)0.f;

  const half8* wfp = (const half8*)wf;
  half8 Bs0[2][2], Bs1[2][2], Bs2[2][2], Bs3[2][2];   // 4-slot ring, distance 3

  // ---- preamble: stage chunk 0; load B sub-steps 0,1,2 into slots 0,1,2 ----
  {
    float4 a0 = *reinterpret_cast<const float4*>(xrow);
    float4 a1 = *reinterpret_cast<const float4*>(xrow + 32);
    float4 a2 = *reinterpret_cast<const float4*>(xrow + 64);
    float4 a3 = *reinterpret_cast<const float4*>(xrow + 96);
    STAGE(0, a0, a1, a2, a3)
    const int ck0 = g * 32;
#pragma unroll
    for (int nt = 0; nt < 2; ++nt) {
      const int ct = w4 + nt * 4;
#pragma unroll
      for (int s = 0; s < 2; ++s) {
        Bs0[nt][s] = wfp[((size_t)(ct * 64 + ck0 + 0) * 2 + s) * 64 + l];
        Bs1[nt][s] = wfp[((size_t)(ct * 64 + ck0 + 1) * 2 + s) * 64 + l];
        Bs2[nt][s] = wfp[((size_t)(ct * 64 + ck0 + 2) * 2 + s) * 64 + l];
      }
    }
  }

#pragma unroll 2
  for (int kc = 0; kc < NKC; ++kc) {
    const int cur = kc & 1;
    const bool more = (kc < NKC - 1);
    float4 p0, p1, p2, p3;
    if (more) {
      const float* xn = xrow + (kc + 1) * BK;
      p0 = *reinterpret_cast<const float4*>(xn);
      p1 = *reinterpret_cast<const float4*>(xn + 32);
      p2 = *reinterpret_cast<const float4*>(xn + 64);
      p3 = *reinterpret_cast<const float4*>(xn + 96);
    }
    // counted barrier: order LDS producer->consumer, leave global loads in flight
    asm volatile("s_waitcnt lgkmcnt(0)" ::: "memory");
    __builtin_amdgcn_s_barrier();

    const _Float16* xsh = xs + ((g * 2 + cur) * 2 + 0) * XREG + cl * LDA + q * 8;
    const _Float16* xsl = xsh + XREG;

    // slot i consumed at sub-step i; loads for sub-step i+3 issued into (i+3)&3
    SUBK(0, Bs0, Bs3, 1)      // ck+3 : this chunk's sub-step 3
    SUBK(1, Bs1, Bs0, more)   // ck+4 : next chunk sub-step 0
    SUBK(2, Bs2, Bs1, more)   // ck+5 : next chunk sub-step 1
    SUBK(3, Bs3, Bs2, more)   // ck+6 : next chunk sub-step 2

    if (more) {
      STAGE(cur ^ 1, p0, p1, p2, p3)
    }
  }

  __syncthreads();   // xs dead; smem becomes Pacc/Vb/Eb (full drain OK, once)

  // ---- split-K merge: group 1 -> LDS, group 0 adds ----
  if (g == 1) {
#pragma unroll
    for (int mt = 0; mt < 2; ++mt)
#pragma unroll
      for (int nt = 0; nt < 2; ++nt)
#pragma unroll
        for (int r = 0; r < 4; ++r)
          Pacc[((((w4 * 2 + mt) * 2 + nt) * 4) + r) * 64 + l] = acc[mt][nt][r];
  }
  __syncthreads();

  if (g == 0) {
#pragma unroll
    for (int mt = 0; mt < 2; ++mt)
#pragma unroll
      for (int nt = 0; nt < 2; ++nt)
#pragma unroll
        for (int r = 0; r < 4; ++r)
          acc[mt][nt][r] += Pacc[((((w4 * 2 + mt) * 2 + nt) * 4) + r) * 64 + l];

    // lane pass: noisy logit + exp, in-register (gate/noise same lane)
#pragma unroll
    for (int mt = 0; mt < 2; ++mt)
#pragma unroll
      for (int r = 0; r < 4; ++r) {
        const int tk = mt * 16 + q * 4 + r;   // C/D layout: row = q*4+r
        float gt = acc[mt][0][r] + bgv;
        float h  = acc[mt][1][r];
        float sp = (h > 20.f) ? h : log1pf(expf(h));
        float v  = gt + rnv[mt][r] * (sp + 0.01f);
        Vb[tk * 66 + c] = v;
        Eb[tk * 66 + c] = expf(v);
      }
  }
  __syncthreads();

  // ---- per-token top-2 + softmax denom (32 threads) ----
  if (t < MT) {
    float v1 = -1e30f, v2 = -1e30f;
    int   i1 = 0, i2 = 0;
    float s = 0.f;
    for (int e = 0; e < EE; ++e) {
      float v = Vb[t * 66 + e];
      s += Eb[t * 66 + e];
      if (v > v1)      { v2 = v1; i2 = i1; v1 = v; i1 = e; }
      else if (v > v2) { v2 = v;  i2 = e; }
    }
    isum[t] = 1.f / s;
    ti[t * 2 + 0] = i1; ti[t * 2 + 1] = i2;
    float e2 = expf(v2 - v1);
    float dn = 1.f + e2;
    tp[t * 2 + 0] = 1.f / dn;
    tp[t * 2 + 1] = e2 / dn;
  }
  __syncthreads();

  // ---- sparse out: patched zero-fill, all 512 threads, one float4 each ----
  {
    const int m  = t >> 4;
    const int c0 = (t & 15) * 4;
    const int i1 = ti[m * 2 + 0], i2 = ti[m * 2 + 1];
    const float p1 = tp[m * 2 + 0], p2 = tp[m * 2 + 1];
    float o[4];
#pragma unroll
    for (int j = 0; j < 4; ++j) {
      const int col = c0 + j;
      o[j] = (col == i1) ? p1 : ((col == i2) ? p2 : 0.f);
    }
    *reinterpret_cast<float4*>(out + (size_t)(t0 + m) * EE + c0) =
        make_float4(o[0], o[1], o[2], o[3]);
  }

  // ---- aux partials: per-expert psum & count ----
  if (t < EE) {
    float s = 0.f;
    int   cn = 0;
#pragma unroll
    for (int m = 0; m < MT; ++m) {
      s  += Eb[m * 66 + t] * isum[m];
      cn += (ti[m * 2 + 0] == t) + (ti[m * 2 + 1] == t);
    }
    atomicAdd(&psum_g[t], s);
    atomicAdd(&cnt_g[t], (float)cn);
  }
}

__global__ void aux_kernel(const float* __restrict__ cnt_g,
                           const float* __restrict__ psum_g,
                           float* __restrict__ out) {
  int e = threadIdx.x;  // 64 lanes, one wave
  float v = cnt_g[e] * psum_g[e];
#pragma unroll
  for (int o = 32; o > 0; o >>= 1) v += __shfl_down(v, o);
  if (e == 0)
    out[(size_t)TOK * EE] = v * ((float)EE / ((float)TOK * (float)TOK));
}

extern "C" void kernel_launch(void* const* d_in, const int* in_sizes, int n_in,
                              void* d_out, int out_size, void* d_ws, size_t ws_size,
                              hipStream_t stream) {
  const float* x  = (const float*)d_in[0];
  const float* rn = (const float*)d_in[1];
  const float* Wg = (const float*)d_in[2];
  const float* bg = (const float*)d_in[3];
  const float* Wn = (const float*)d_in[4];
  float* out    = (float*)d_out;
  float* cnt_g  = (float*)d_ws;                      // [0..63]
  float* psum_g = cnt_g + EE;                        // [64..127]
  _Float16* wf  = (_Float16*)((float*)d_ws + 256);   // 1 MiB of pre-split W frags

  build_wf<<<256, 128, 0, stream>>>(Wg, Wn, wf, cnt_g);
  gating_kernel<<<NBLK, 512, 0, stream>>>(x, rn, wf, bg, out, cnt_g, psum_g);
  aux_kernel<<<1, 64, 0, stream>>>(cnt_g, psum_g, out);
}

// Round 11
// 260.747 us; speedup vs baseline: 1.0269x; 1.0269x over previous
//
#include <hip/hip_runtime.h>
#include <math.h>

#define TOK 16384
#define DD  2048
#define EE  64
#define MT  32           // tokens per block
#define BK  128          // k per chunk = 4 MFMA sub-steps of 32
#define NKC 8            // chunks per K-group (group covers 1024)
#define LDA 138          // halves per row per split (276B = 69-word stride; 25x fewer bank conflicts than 136, measured R10)
#define XREG (MT * LDA)  // halves per (g,buf,split) region
#define NBLK (TOK / MT)  // 512 gating blocks

typedef _Float16 half4v __attribute__((ext_vector_type(4)));
typedef _Float16 half8  __attribute__((ext_vector_type(8)));
typedef float    floatx4 __attribute__((ext_vector_type(4)));

// ---- W pre-split: f32 -> (hi,lo) f16, frag-major layout ----
// wf frag index ((ct*64+kc)*2+s)*64+lane, 8 halves each (kc = 32-k chunk 0..63).
// ct 0..3 = gate col-tiles (cols ct*16+cl), ct 4..7 = noise col-tiles.
// Block 0 also zeroes the aux workspace (stream order covers gating_kernel).
__global__ void build_wf(const float* __restrict__ Wg, const float* __restrict__ Wn,
                         _Float16* __restrict__ wf, float* __restrict__ zws) {
  if (blockIdx.x == 0 && threadIdx.x < 128) zws[threadIdx.x] = 0.f;
  int tid  = blockIdx.x * 128 + threadIdx.x;   // 32768 threads
  int lane = tid & 63;
  int kc   = (tid >> 6) & 63;
  int ct   = tid >> 12;                        // 0..7
  int col  = (ct & 3) * 16 + (lane & 15);
  int k    = kc * 32 + (lane >> 4) * 8;
  const float* W = (ct < 4) ? Wg : Wn;
  const float* src = W + (size_t)col * DD + k;
  float4 a = *reinterpret_cast<const float4*>(src);
  float4 b = *reinterpret_cast<const float4*>(src + 4);
  float v[8] = {a.x, a.y, a.z, a.w, b.x, b.y, b.z, b.w};
  half8 hi, lo;
#pragma unroll
  for (int j = 0; j < 8; ++j) {
    _Float16 h = (_Float16)v[j];
    hi[j] = h;
    lo[j] = (_Float16)(v[j] - (float)h);
  }
  size_t base = (((size_t)(ct * 64 + kc) * 2 + 0) * 64 + lane) * 8;
  *reinterpret_cast<half8*>(wf + base)       = hi;
  *reinterpret_cast<half8*>(wf + base + 512) = lo;
}

// Convert+store one 128-float chunk row-slice (4x float4) into buffer BUF.
#define STAGE(BUF, P0, P1, P2, P3)                                              \
  {                                                                             \
    float4 pav[4] = {P0, P1, P2, P3};                                           \
    _Float16* xh = xs + ((g * 2 + (BUF)) * 2 + 0) * XREG + stok * LDA + skof;   \
    _Float16* xl = xh + XREG;                                                   \
    _Pragma("unroll")                                                           \
    for (int j = 0; j < 4; ++j) {                                               \
      float v[4] = {pav[j].x, pav[j].y, pav[j].z, pav[j].w};                    \
      half4v hi, lo;                                                            \
      _Pragma("unroll")                                                         \
      for (int jj = 0; jj < 4; ++jj) {                                          \
        _Float16 h = (_Float16)v[jj];                                           \
        hi[jj] = h;                                                             \
        lo[jj] = (_Float16)(v[jj] - (float)h);                                  \
      }                                                                         \
      *reinterpret_cast<half4v*>(xh + j * 32) = hi;                             \
      *reinterpret_cast<half4v*>(xl + j * 32) = lo;                             \
    }                                                                           \
  }

// One 32-k MFMA sub-step: consume B slot SC, prefetch next sub-step into SP
// (2-slot ring, distance 1 — proven to fit in 64 VGPR with no spill, R7).
// MFMA order (hi*hi, hi*lo, lo*hi) and k-order identical to the verified kernel.
#define SUBK(KK, SC, SP, DOPF)                                                  \
  {                                                                             \
    half8 Ah[2], Al[2];                                                         \
    _Pragma("unroll")                                                           \
    for (int mt = 0; mt < 2; ++mt) {                                            \
      Ah[mt] = *reinterpret_cast<const half8*>(xsh + (mt * 16) * LDA + (KK) * 32); \
      Al[mt] = *reinterpret_cast<const half8*>(xsl + (mt * 16) * LDA + (KK) * 32); \
    }                                                                           \
    if (DOPF) {                                                                 \
      const int ck = g * 32 + kc * 4 + (KK) + 1;                                \
      _Pragma("unroll")                                                         \
      for (int nt = 0; nt < 2; ++nt) {                                          \
        const int ct = w4 + nt * 4;                                             \
        _Pragma("unroll")                                                       \
        for (int s = 0; s < 2; ++s)                                             \
          SP[nt][s] = wfp[((size_t)(ct * 64 + ck) * 2 + s) * 64 + l];           \
      }                                                                         \
    }                                                                           \
    _Pragma("unroll")                                                           \
    for (int mt = 0; mt < 2; ++mt)                                              \
      _Pragma("unroll")                                                         \
      for (int nt = 0; nt < 2; ++nt)                                            \
        acc[mt][nt] = __builtin_amdgcn_mfma_f32_16x16x32_f16(Ah[mt], SC[nt][0], acc[mt][nt], 0, 0, 0); \
    _Pragma("unroll")                                                           \
    for (int mt = 0; mt < 2; ++mt)                                              \
      _Pragma("unroll")                                                         \
      for (int nt = 0; nt < 2; ++nt)                                            \
        acc[mt][nt] = __builtin_amdgcn_mfma_f32_16x16x32_f16(Ah[mt], SC[nt][1], acc[mt][nt], 0, 0, 0); \
    _Pragma("unroll")                                                           \
    for (int mt = 0; mt < 2; ++mt)                                              \
      _Pragma("unroll")                                                         \
      for (int nt = 0; nt < 2; ++nt)                                            \
        acc[mt][nt] = __builtin_amdgcn_mfma_f32_16x16x32_f16(Al[mt], SC[nt][0], acc[mt][nt], 0, 0, 0); \
  }

// LDS plan:
//   K-phase : xs[(g*2+buf)*2+split][32*LDA] halves = 8 regions x 8832 B = 70656 B
//   E-phase : overlay — Pacc 64x64 f32 @0 | Vb[32][66] @16384 | Eb[32][66] @24832
//             isum @33280 | ti @33408 | tp @33664  (33920 B < 70656)
__global__ __launch_bounds__(512, 4)
void gating_kernel(const float* __restrict__ x, const float* __restrict__ rn,
                   const _Float16* __restrict__ wf, const float* __restrict__ bg,
                   float* __restrict__ out,
                   float* __restrict__ cnt_g, float* __restrict__ psum_g) {
  __shared__ char smem[70656];
  _Float16* xs   = (_Float16*)smem;
  float*    Pacc = (float*)smem;
  float*    Vb   = (float*)(smem + 16384);
  float*    Eb   = (float*)(smem + 24832);
  float*    isum = (float*)(smem + 33280);
  int*      ti   = (int*)(smem + 33408);
  float*    tp   = (float*)(smem + 33664);

  const int t  = threadIdx.x;
  const int g  = t >> 8;        // K-group: 0 -> K[0,1024), 1 -> K[1024,2048)
  const int tg = t & 255;
  const int w4 = tg >> 6;       // ct-pair 0..3 -> expert cols [w4*16, +16)
  const int l  = t & 63;
  const int q  = l >> 4;
  const int cl = l & 15;
  const int c  = w4 * 16 + cl;
  const int t0 = blockIdx.x * MT;

  // x staging (per group): thread covers token tg>>3, float-offset (tg&7)*4
  const int stok = tg >> 3;
  const int skof = (tg & 7) * 4;
  const float* xrow = x + (size_t)(t0 + stok) * DD + g * (NKC * BK) + skof;

  // epilogue operands (group 0 only)
  float bgv = 0.f;
  float rnv[2][4] = {{0.f,0.f,0.f,0.f},{0.f,0.f,0.f,0.f}};
  if (g == 0) {
    bgv = bg[c];
#pragma unroll
    for (int mt = 0; mt < 2; ++mt)
#pragma unroll
      for (int r = 0; r < 4; ++r)
        rnv[mt][r] = rn[(size_t)(t0 + mt * 16 + q * 4 + r) * EE + c];
  }

  floatx4 acc[2][2];
#pragma unroll
  for (int mt = 0; mt < 2; ++mt)
#pragma unroll
    for (int nt = 0; nt < 2; ++nt) acc[mt][nt] = (floatx4)0.f;

  const half8* wfp = (const half8*)wf;
  half8 Bs0[2][2], Bs1[2][2];   // static 2-slot ring, distance-1 prefetch

  // ---- preamble: stage chunk 0 of this group; load B sub-step 0 ----
  {
    float4 a0 = *reinterpret_cast<const float4*>(xrow);
    float4 a1 = *reinterpret_cast<const float4*>(xrow + 32);
    float4 a2 = *reinterpret_cast<const float4*>(xrow + 64);
    float4 a3 = *reinterpret_cast<const float4*>(xrow + 96);
    STAGE(0, a0, a1, a2, a3)
    const int ck0 = g * 32;
#pragma unroll
    for (int nt = 0; nt < 2; ++nt) {
      const int ct = w4 + nt * 4;
#pragma unroll
      for (int s = 0; s < 2; ++s)
        Bs0[nt][s] = wfp[((size_t)(ct * 64 + ck0) * 2 + s) * 64 + l];
    }
  }

#pragma unroll 2
  for (int kc = 0; kc < NKC; ++kc) {
    const int cur = kc & 1;
    const bool more = (kc < NKC - 1);
    float4 p0, p1, p2, p3;
    if (more) {
      const float* xn = xrow + (kc + 1) * BK;
      p0 = *reinterpret_cast<const float4*>(xn);
      p1 = *reinterpret_cast<const float4*>(xn + 32);
      p2 = *reinterpret_cast<const float4*>(xn + 64);
      p3 = *reinterpret_cast<const float4*>(xn + 96);
    }
    // counted barrier: order LDS producer->consumer, leave global loads in flight
    asm volatile("s_waitcnt lgkmcnt(0)" ::: "memory");
    __builtin_amdgcn_s_barrier();

    const _Float16* xsh = xs + ((g * 2 + cur) * 2 + 0) * XREG + cl * LDA + q * 8;
    const _Float16* xsl = xsh + XREG;

    SUBK(0, Bs0, Bs1, 1)
    SUBK(1, Bs1, Bs0, 1)
    SUBK(2, Bs0, Bs1, 1)
    SUBK(3, Bs1, Bs0, more)   // prefetches next chunk's sub-step 0 into Bs0

    if (more) {
      STAGE(cur ^ 1, p0, p1, p2, p3)
    }
  }

  __syncthreads();   // xs dead; smem becomes Pacc/Vb/Eb (full drain OK, once)

  // ---- split-K merge: group 1 -> LDS, group 0 adds ----
  if (g == 1) {
#pragma unroll
    for (int mt = 0; mt < 2; ++mt)
#pragma unroll
      for (int nt = 0; nt < 2; ++nt)
#pragma unroll
        for (int r = 0; r < 4; ++r)
          Pacc[((((w4 * 2 + mt) * 2 + nt) * 4) + r) * 64 + l] = acc[mt][nt][r];
  }
  __syncthreads();

  if (g == 0) {
#pragma unroll
    for (int mt = 0; mt < 2; ++mt)
#pragma unroll
      for (int nt = 0; nt < 2; ++nt)
#pragma unroll
        for (int r = 0; r < 4; ++r)
          acc[mt][nt][r] += Pacc[((((w4 * 2 + mt) * 2 + nt) * 4) + r) * 64 + l];

    // lane pass: noisy logit + exp, in-register (gate/noise same lane)
#pragma unroll
    for (int mt = 0; mt < 2; ++mt)
#pragma unroll
      for (int r = 0; r < 4; ++r) {
        const int tk = mt * 16 + q * 4 + r;   // C/D layout: row = q*4+r
        float gt = acc[mt][0][r] + bgv;
        float h  = acc[mt][1][r];
        float sp = (h > 20.f) ? h : log1pf(expf(h));
        float v  = gt + rnv[mt][r] * (sp + 0.01f);
        Vb[tk * 66 + c] = v;
        Eb[tk * 66 + c] = expf(v);
      }
  }
  __syncthreads();

  // ---- per-token top-2 + softmax denom (32 threads) ----
  if (t < MT) {
    float v1 = -1e30f, v2 = -1e30f;
    int   i1 = 0, i2 = 0;
    float s = 0.f;
    for (int e = 0; e < EE; ++e) {
      float v = Vb[t * 66 + e];
      s += Eb[t * 66 + e];
      if (v > v1)      { v2 = v1; i2 = i1; v1 = v; i1 = e; }
      else if (v > v2) { v2 = v;  i2 = e; }
    }
    isum[t] = 1.f / s;
    ti[t * 2 + 0] = i1; ti[t * 2 + 1] = i2;
    float e2 = expf(v2 - v1);
    float dn = 1.f + e2;
    tp[t * 2 + 0] = 1.f / dn;
    tp[t * 2 + 1] = e2 / dn;
  }
  __syncthreads();

  // ---- sparse out: patched zero-fill, all 512 threads, one float4 each ----
  {
    const int m  = t >> 4;
    const int c0 = (t & 15) * 4;
    const int i1 = ti[m * 2 + 0], i2 = ti[m * 2 + 1];
    const float p1 = tp[m * 2 + 0], p2 = tp[m * 2 + 1];
    float o[4];
#pragma unroll
    for (int j = 0; j < 4; ++j) {
      const int col = c0 + j;
      o[j] = (col == i1) ? p1 : ((col == i2) ? p2 : 0.f);
    }
    *reinterpret_cast<float4*>(out + (size_t)(t0 + m) * EE + c0) =
        make_float4(o[0], o[1], o[2], o[3]);
  }

  // ---- aux partials: per-expert psum & count ----
  if (t < EE) {
    float s = 0.f;
    int   cn = 0;
#pragma unroll
    for (int m = 0; m < MT; ++m) {
      s  += Eb[m * 66 + t] * isum[m];
      cn += (ti[m * 2 + 0] == t) + (ti[m * 2 + 1] == t);
    }
    atomicAdd(&psum_g[t], s);
    atomicAdd(&cnt_g[t], (float)cn);
  }
}

__global__ void aux_kernel(const float* __restrict__ cnt_g,
                           const float* __restrict__ psum_g,
                           float* __restrict__ out) {
  int e = threadIdx.x;  // 64 lanes, one wave
  float v = cnt_g[e] * psum_g[e];
#pragma unroll
  for (int o = 32; o > 0; o >>= 1) v += __shfl_down(v, o);
  if (e == 0)
    out[(size_t)TOK * EE] = v * ((float)EE / ((float)TOK * (float)TOK));
}

extern "C" void kernel_launch(void* const* d_in, const int* in_sizes, int n_in,
                              void* d_out, int out_size, void* d_ws, size_t ws_size,
                              hipStream_t stream) {
  const float* x  = (const float*)d_in[0];
  const float* rn = (const float*)d_in[1];
  const float* Wg = (const float*)d_in[2];
  const float* bg = (const float*)d_in[3];
  const float* Wn = (const float*)d_in[4];
  float* out    = (float*)d_out;
  float* cnt_g  = (float*)d_ws;                      // [0..63]
  float* psum_g = cnt_g + EE;                        // [64..127]
  _Float16* wf  = (_Float16*)((float*)d_ws + 256);   // 1 MiB of pre-split W frags

  build_wf<<<256, 128, 0, stream>>>(Wg, Wn, wf, cnt_g);
  gating_kernel<<<NBLK, 512, 0, stream>>>(x, rn, wf, bg, out, cnt_g, psum_g);
  aux_kernel<<<1, 64, 0, stream>>>(cnt_g, psum_g, out);
}

// Round 12
// 226.217 us; speedup vs baseline: 1.1836x; 1.1526x over previous
//
#include <hip/hip_runtime.h>
#include <math.h>

#define TOK 16384
#define DD  2048
#define EE  64
#define MT  32           // tokens per block
#define BK  128          // k per chunk = 4 MFMA sub-steps of 32
#define NKC 8            // chunks per K-group (group covers 1024)
#define LDA 136          // halves per row per split (272B stride; MUST be 0 mod 8 for b128 alignment — R11)
#define XREG (MT * LDA)  // halves per (g,buf,split) region
#define NBLK (TOK / MT)  // 512 gating blocks

typedef _Float16 half8  __attribute__((ext_vector_type(8)));
typedef float    floatx4 __attribute__((ext_vector_type(4)));

// ---- W pre-split: f32 -> (hi,lo) f16, frag-major layout ----
// wf frag index ((ct*64+kc)*2+s)*64+lane, 8 halves each (kc = 32-k chunk 0..63).
// ct 0..3 = gate col-tiles (cols ct*16+cl), ct 4..7 = noise col-tiles.
// Block 0 also zeroes the aux workspace (stream order covers gating_kernel).
__global__ void build_wf(const float* __restrict__ Wg, const float* __restrict__ Wn,
                         _Float16* __restrict__ wf, float* __restrict__ zws) {
  if (blockIdx.x == 0 && threadIdx.x < 128) zws[threadIdx.x] = 0.f;
  int tid  = blockIdx.x * 128 + threadIdx.x;   // 32768 threads
  int lane = tid & 63;
  int kc   = (tid >> 6) & 63;
  int ct   = tid >> 12;                        // 0..7
  int col  = (ct & 3) * 16 + (lane & 15);
  int k    = kc * 32 + (lane >> 4) * 8;
  const float* W = (ct < 4) ? Wg : Wn;
  const float* src = W + (size_t)col * DD + k;
  float4 a = *reinterpret_cast<const float4*>(src);
  float4 b = *reinterpret_cast<const float4*>(src + 4);
  float v[8] = {a.x, a.y, a.z, a.w, b.x, b.y, b.z, b.w};
  half8 hi, lo;
#pragma unroll
  for (int j = 0; j < 8; ++j) {
    _Float16 h = (_Float16)v[j];
    hi[j] = h;
    lo[j] = (_Float16)(v[j] - (float)h);
  }
  size_t base = (((size_t)(ct * 64 + kc) * 2 + 0) * 64 + lane) * 8;
  *reinterpret_cast<half8*>(wf + base)       = hi;
  *reinterpret_cast<half8*>(wf + base + 512) = lo;
}

// Convert+store one 16-contiguous-float row-slice into buffer BUF.
// Thread covers floats [skof, skof+16) of token row stok -> 16 contiguous
// halves per split = 2x ds_write_b128 each (vs 8x b64 strided before).
// Write banks: (i + 2j + u) mod 8 -> exactly 8 lanes per 16B bank-group =
// minimum-even, i.e. conflict-free (the old strided pattern was 4-way
// clustered on even banks -> the 3.27M SQ_LDS_BANK_CONFLICT). Read side
// byte-identical to the verified R7 layout.
#define STAGE(BUF, P0, P1, P2, P3)                                              \
  {                                                                             \
    float4 pav[4] = {P0, P1, P2, P3};                                           \
    _Float16* xh = xs + ((g * 2 + (BUF)) * 2 + 0) * XREG + stok * LDA + skof;   \
    _Float16* xl = xh + XREG;                                                   \
    half8 hv[2], lv[2];                                                         \
    _Pragma("unroll")                                                           \
    for (int j = 0; j < 4; ++j) {                                               \
      float v[4] = {pav[j].x, pav[j].y, pav[j].z, pav[j].w};                    \
      _Pragma("unroll")                                                         \
      for (int jj = 0; jj < 4; ++jj) {                                          \
        _Float16 h = (_Float16)v[jj];                                           \
        hv[j >> 1][(j & 1) * 4 + jj] = h;                                       \
        lv[j >> 1][(j & 1) * 4 + jj] = (_Float16)(v[jj] - (float)h);            \
      }                                                                         \
    }                                                                           \
    *reinterpret_cast<half8*>(xh)     = hv[0];                                  \
    *reinterpret_cast<half8*>(xh + 8) = hv[1];                                  \
    *reinterpret_cast<half8*>(xl)     = lv[0];                                  \
    *reinterpret_cast<half8*>(xl + 8) = lv[1];                                  \
  }

// One 32-k MFMA sub-step: consume B slot SC, prefetch next sub-step into SP
// (2-slot ring, distance 1 — fits in 64 VGPR, no spill: R7-verified).
// MFMA order (hi*hi, hi*lo, lo*hi) and k-order identical to the verified kernel.
#define SUBK(KK, SC, SP, DOPF)                                                  \
  {                                                                             \
    half8 Ah[2], Al[2];                                                         \
    _Pragma("unroll")                                                           \
    for (int mt = 0; mt < 2; ++mt) {                                            \
      Ah[mt] = *reinterpret_cast<const half8*>(xsh + (mt * 16) * LDA + (KK) * 32); \
      Al[mt] = *reinterpret_cast<const half8*>(xsl + (mt * 16) * LDA + (KK) * 32); \
    }                                                                           \
    if (DOPF) {                                                                 \
      const int ck = g * 32 + kc * 4 + (KK) + 1;                                \
      _Pragma("unroll")                                                         \
      for (int nt = 0; nt < 2; ++nt) {                                          \
        const int ct = w4 + nt * 4;                                             \
        _Pragma("unroll")                                                       \
        for (int s = 0; s < 2; ++s)                                             \
          SP[nt][s] = wfp[((size_t)(ct * 64 + ck) * 2 + s) * 64 + l];           \
      }                                                                         \
    }                                                                           \
    _Pragma("unroll")                                                           \
    for (int mt = 0; mt < 2; ++mt)                                              \
      _Pragma("unroll")                                                         \
      for (int nt = 0; nt < 2; ++nt)                                            \
        acc[mt][nt] = __builtin_amdgcn_mfma_f32_16x16x32_f16(Ah[mt], SC[nt][0], acc[mt][nt], 0, 0, 0); \
    _Pragma("unroll")                                                           \
    for (int mt = 0; mt < 2; ++mt)                                              \
      _Pragma("unroll")                                                         \
      for (int nt = 0; nt < 2; ++nt)                                            \
        acc[mt][nt] = __builtin_amdgcn_mfma_f32_16x16x32_f16(Ah[mt], SC[nt][1], acc[mt][nt], 0, 0, 0); \
    _Pragma("unroll")                                                           \
    for (int mt = 0; mt < 2; ++mt)                                              \
      _Pragma("unroll")                                                         \
      for (int nt = 0; nt < 2; ++nt)                                            \
        acc[mt][nt] = __builtin_amdgcn_mfma_f32_16x16x32_f16(Al[mt], SC[nt][0], acc[mt][nt], 0, 0, 0); \
  }

// LDS plan:
//   K-phase : xs[(g*2+buf)*2+split][32*LDA] halves = 8 regions x 8704 B = 69632 B
//   E-phase : overlay — Pacc 64x64 f32 @0 | Vb[32][66] @16384 | Eb[32][66] @24832
//             isum @33280 | ti @33408 | tp @33664  (33920 B < 69632)
__global__ __launch_bounds__(512, 4)
void gating_kernel(const float* __restrict__ x, const float* __restrict__ rn,
                   const _Float16* __restrict__ wf, const float* __restrict__ bg,
                   float* __restrict__ out,
                   float* __restrict__ cnt_g, float* __restrict__ psum_g) {
  __shared__ char smem[69632];
  _Float16* xs   = (_Float16*)smem;
  float*    Pacc = (float*)smem;
  float*    Vb   = (float*)(smem + 16384);
  float*    Eb   = (float*)(smem + 24832);
  float*    isum = (float*)(smem + 33280);
  int*      ti   = (int*)(smem + 33408);
  float*    tp   = (float*)(smem + 33664);

  const int t  = threadIdx.x;
  const int g  = t >> 8;        // K-group: 0 -> K[0,1024), 1 -> K[1024,2048)
  const int tg = t & 255;
  const int w4 = tg >> 6;       // ct-pair 0..3 -> expert cols [w4*16, +16)
  const int l  = t & 63;
  const int q  = l >> 4;
  const int cl = l & 15;
  const int c  = w4 * 16 + cl;
  const int t0 = blockIdx.x * MT;

  // x staging (per group): thread covers token tg>>3, floats [(tg&7)*16, +16)
  const int stok = tg >> 3;
  const int skof = (tg & 7) * 16;
  const float* xrow = x + (size_t)(t0 + stok) * DD + g * (NKC * BK) + skof;

  // epilogue operands (group 0 only)
  float bgv = 0.f;
  float rnv[2][4] = {{0.f,0.f,0.f,0.f},{0.f,0.f,0.f,0.f}};
  if (g == 0) {
    bgv = bg[c];
#pragma unroll
    for (int mt = 0; mt < 2; ++mt)
#pragma unroll
      for (int r = 0; r < 4; ++r)
        rnv[mt][r] = rn[(size_t)(t0 + mt * 16 + q * 4 + r) * EE + c];
  }

  floatx4 acc[2][2];
#pragma unroll
  for (int mt = 0; mt < 2; ++mt)
#pragma unroll
    for (int nt = 0; nt < 2; ++nt) acc[mt][nt] = (floatx4)0.f;

  const half8* wfp = (const half8*)wf;
  half8 Bs0[2][2], Bs1[2][2];   // static 2-slot ring, distance-1 prefetch

  // ---- preamble: stage chunk 0 of this group; load B sub-step 0 ----
  {
    float4 a0 = *reinterpret_cast<const float4*>(xrow);
    float4 a1 = *reinterpret_cast<const float4*>(xrow + 4);
    float4 a2 = *reinterpret_cast<const float4*>(xrow + 8);
    float4 a3 = *reinterpret_cast<const float4*>(xrow + 12);
    STAGE(0, a0, a1, a2, a3)
    const int ck0 = g * 32;
#pragma unroll
    for (int nt = 0; nt < 2; ++nt) {
      const int ct = w4 + nt * 4;
#pragma unroll
      for (int s = 0; s < 2; ++s)
        Bs0[nt][s] = wfp[((size_t)(ct * 64 + ck0) * 2 + s) * 64 + l];
    }
  }

#pragma unroll 2
  for (int kc = 0; kc < NKC; ++kc) {
    const int cur = kc & 1;
    const bool more = (kc < NKC - 1);
    float4 p0, p1, p2, p3;
    if (more) {
      const float* xn = xrow + (kc + 1) * BK;
      p0 = *reinterpret_cast<const float4*>(xn);
      p1 = *reinterpret_cast<const float4*>(xn + 4);
      p2 = *reinterpret_cast<const float4*>(xn + 8);
      p3 = *reinterpret_cast<const float4*>(xn + 12);
    }
    // counted barrier: order LDS producer->consumer, leave global loads in flight
    asm volatile("s_waitcnt lgkmcnt(0)" ::: "memory");
    __builtin_amdgcn_s_barrier();

    const _Float16* xsh = xs + ((g * 2 + cur) * 2 + 0) * XREG + cl * LDA + q * 8;
    const _Float16* xsl = xsh + XREG;

    SUBK(0, Bs0, Bs1, 1)
    SUBK(1, Bs1, Bs0, 1)
    SUBK(2, Bs0, Bs1, 1)
    SUBK(3, Bs1, Bs0, more)   // prefetches next chunk's sub-step 0 into Bs0

    if (more) {
      STAGE(cur ^ 1, p0, p1, p2, p3)
    }
  }

  __syncthreads();   // xs dead; smem becomes Pacc/Vb/Eb (full drain OK, once)

  // ---- split-K merge: group 1 -> LDS, group 0 adds ----
  if (g == 1) {
#pragma unroll
    for (int mt = 0; mt < 2; ++mt)
#pragma unroll
      for (int nt = 0; nt < 2; ++nt)
#pragma unroll
        for (int r = 0; r < 4; ++r)
          Pacc[((((w4 * 2 + mt) * 2 + nt) * 4) + r) * 64 + l] = acc[mt][nt][r];
  }
  __syncthreads();

  if (g == 0) {
#pragma unroll
    for (int mt = 0; mt < 2; ++mt)
#pragma unroll
      for (int nt = 0; nt < 2; ++nt)
#pragma unroll
        for (int r = 0; r < 4; ++r)
          acc[mt][nt][r] += Pacc[((((w4 * 2 + mt) * 2 + nt) * 4) + r) * 64 + l];

    // lane pass: noisy logit + exp, in-register (gate/noise same lane)
#pragma unroll
    for (int mt = 0; mt < 2; ++mt)
#pragma unroll
      for (int r = 0; r < 4; ++r) {
        const int tk = mt * 16 + q * 4 + r;   // C/D layout: row = q*4+r
        float gt = acc[mt][0][r] + bgv;
        float h  = acc[mt][1][r];
        float sp = (h > 20.f) ? h : log1pf(expf(h));
        float v  = gt + rnv[mt][r] * (sp + 0.01f);
        Vb[tk * 66 + c] = v;
        Eb[tk * 66 + c] = expf(v);
      }
  }
  __syncthreads();

  // ---- per-token top-2 + softmax denom (32 threads) ----
  if (t < MT) {
    float v1 = -1e30f, v2 = -1e30f;
    int   i1 = 0, i2 = 0;
    float s = 0.f;
    for (int e = 0; e < EE; ++e) {
      float v = Vb[t * 66 + e];
      s += Eb[t * 66 + e];
      if (v > v1)      { v2 = v1; i2 = i1; v1 = v; i1 = e; }
      else if (v > v2) { v2 = v;  i2 = e; }
    }
    isum[t] = 1.f / s;
    ti[t * 2 + 0] = i1; ti[t * 2 + 1] = i2;
    float e2 = expf(v2 - v1);
    float dn = 1.f + e2;
    tp[t * 2 + 0] = 1.f / dn;
    tp[t * 2 + 1] = e2 / dn;
  }
  __syncthreads();

  // ---- sparse out: patched zero-fill, all 512 threads, one float4 each ----
  {
    const int m  = t >> 4;
    const int c0 = (t & 15) * 4;
    const int i1 = ti[m * 2 + 0], i2 = ti[m * 2 + 1];
    const float p1 = tp[m * 2 + 0], p2 = tp[m * 2 + 1];
    float o[4];
#pragma unroll
    for (int j = 0; j < 4; ++j) {
      const int col = c0 + j;
      o[j] = (col == i1) ? p1 : ((col == i2) ? p2 : 0.f);
    }
    *reinterpret_cast<float4*>(out + (size_t)(t0 + m) * EE + c0) =
        make_float4(o[0], o[1], o[2], o[3]);
  }

  // ---- aux partials: per-expert psum & count ----
  if (t < EE) {
    float s = 0.f;
    int   cn = 0;
#pragma unroll
    for (int m = 0; m < MT; ++m) {
      s  += Eb[m * 66 + t] * isum[m];
      cn += (ti[m * 2 + 0] == t) + (ti[m * 2 + 1] == t);
    }
    atomicAdd(&psum_g[t], s);
    atomicAdd(&cnt_g[t], (float)cn);
  }
}

__global__ void aux_kernel(const float* __restrict__ cnt_g,
                           const float* __restrict__ psum_g,
                           float* __restrict__ out) {
  int e = threadIdx.x;  // 64 lanes, one wave
  float v = cnt_g[e] * psum_g[e];
#pragma unroll
  for (int o = 32; o > 0; o >>= 1) v += __shfl_down(v, o);
  if (e == 0)
    out[(size_t)TOK * EE] = v * ((float)EE / ((float)TOK * (float)TOK));
}

extern "C" void kernel_launch(void* const* d_in, const int* in_sizes, int n_in,
                              void* d_out, int out_size, void* d_ws, size_t ws_size,
                              hipStream_t stream) {
  const float* x  = (const float*)d_in[0];
  const float* rn = (const float*)d_in[1];
  const float* Wg = (const float*)d_in[2];
  const float* bg = (const float*)d_in[3];
  const float* Wn = (const float*)d_in[4];
  float* out    = (float*)d_out;
  float* cnt_g  = (float*)d_ws;                      // [0..63]
  float* psum_g = cnt_g + EE;                        // [64..127]
  _Float16* wf  = (_Float16*)((float*)d_ws + 256);   // 1 MiB of pre-split W frags

  build_wf<<<256, 128, 0, stream>>>(Wg, Wn, wf, cnt_g);
  gating_kernel<<<NBLK, 512, 0, stream>>>(x, rn, wf, bg, out, cnt_g, psum_g);
  aux_kernel<<<1, 64, 0, stream>>>(cnt_g, psum_g, out);
}